// Round 1
// baseline (370.205 us; speedup 1.0000x reference)
//
#include <hip/hip_runtime.h>
#include <stdint.h>

#define T_DIM 2048
#define B_DIM 16
#define H_DIM 1024
#define M_DIM (T_DIM * B_DIM)   // 32768 rows
#define BK 64

typedef __attribute__((ext_vector_type(8))) short bf16x8;
typedef __attribute__((ext_vector_type(4))) float floatx4;

__device__ inline unsigned short f2bf(float f) {
  union { float f; unsigned int u; } c; c.f = f;
  unsigned int u = c.u;
  return (unsigned short)((u + 0x7FFFu + ((u >> 16) & 1u)) >> 16);  // RNE
}

__device__ inline float fast_tanh(float x) {
  float e = __expf(2.0f * x);
  return 1.0f - 2.0f / (e + 1.0f);   // exact at +-inf, ~1e-6 rel err
}

// ---------------- X fp32 -> bf16 ----------------
__global__ void convert_x_kernel(const float* __restrict__ x,
                                 unsigned short* __restrict__ xb) {
  size_t i = ((size_t)blockIdx.x * 256 + threadIdx.x) * 4;
  float4 v = *(const float4*)(x + i);
  ushort4 o;
  o.x = f2bf(v.x); o.y = f2bf(v.y); o.z = f2bf(v.z); o.w = f2bf(v.w);
  *(ushort4*)(xb + i) = o;
}

// ---------------- W[K][N] fp32 -> Wt[N][K] bf16 ----------------
__global__ void transpose_w_kernel(const float* __restrict__ w,
                                   unsigned short* __restrict__ wt) {
  __shared__ float tile[32][33];
  int tx = threadIdx.x, ty = threadIdx.y;
  int n0 = blockIdx.x * 32, k0 = blockIdx.y * 32;
  for (int i = ty; i < 32; i += 8)
    tile[i][tx] = w[(size_t)(k0 + i) * H_DIM + n0 + tx];
  __syncthreads();
  for (int i = ty; i < 32; i += 8)
    wt[(size_t)(n0 + i) * H_DIM + k0 + tx] = f2bf(tile[tx][i]);
}

// ---------------- scores = tanh(X@W)@proj ----------------
// grid = 256 M-blocks * 4 N-splits. Block tile 128(M) x 128(N) per n0 iter,
// 4 waves in 2x2 quadrants of 64x64. BK=64 LDS stages via global_load_lds,
// XOR-swizzled 16B chunks (<=2-way bank conflicts on ds_read_b128).
__global__ __launch_bounds__(256, 3)
void score_gemm_kernel(const unsigned short* __restrict__ Xb,
                       const unsigned short* __restrict__ Wt,
                       const float* __restrict__ proj,
                       float* __restrict__ scores) {
  __shared__ __align__(16) unsigned short ldsA[128 * BK];
  __shared__ __align__(16) unsigned short ldsB[128 * BK];

  const int tid  = threadIdx.x;
  const int lane = tid & 63;
  const int wave = tid >> 6;
  const int wy = wave >> 1, wx = wave & 1;
  const int quad = lane >> 4, l16 = lane & 15;

  const int bm    = blockIdx.x >> 2;   // 0..255 : 128-row slab
  const int split = blockIdx.x & 3;    // 0..3   : 256-col slab of N
  const int m0 = bm * 128;
  const int nbase = split * 256;

  // precompute staging offsets (invariant over k0/n0)
  int ldsOff[4];   // chunk base (in 16B chunks) for this wave's call i
  int rowOff[4];   // row*H + cg*8 element offset
  #pragma unroll
  for (int i = 0; i < 4; ++i) {
    int cb = (i * 4 + wave) * 64;        // 64 chunks per wave-call
    int s = cb + lane;
    int row = s >> 3, cs = s & 7;
    int cg = cs ^ (row & 7);             // un-swizzle: global chunk
    ldsOff[i] = cb;
    rowOff[i] = row * H_DIM + cg * 8;
  }

  float sc[4][4];                        // partial scores [rsub][reg]
  #pragma unroll
  for (int a = 0; a < 4; ++a)
    #pragma unroll
    for (int b = 0; b < 4; ++b) sc[a][b] = 0.0f;

  for (int n0 = nbase; n0 < nbase + 256; n0 += 128) {
    floatx4 acc[4][4];
    #pragma unroll
    for (int a = 0; a < 4; ++a)
      #pragma unroll
      for (int b = 0; b < 4; ++b) acc[a][b] = (floatx4){0.f, 0.f, 0.f, 0.f};

    for (int k0 = 0; k0 < H_DIM; k0 += BK) {
      // ---- stage A[128xBK] and B[128xBK] ----
      #pragma unroll
      for (int i = 0; i < 4; ++i) {
        const unsigned short* ga = Xb + (size_t)m0 * H_DIM + rowOff[i] + k0;
        __builtin_amdgcn_global_load_lds(
            (const __attribute__((address_space(1))) void*)ga,
            (__attribute__((address_space(3))) void*)(&ldsA[ldsOff[i] * 8]),
            16, 0, 0);
        const unsigned short* gb = Wt + (size_t)n0 * H_DIM + rowOff[i] + k0;
        __builtin_amdgcn_global_load_lds(
            (const __attribute__((address_space(1))) void*)gb,
            (__attribute__((address_space(3))) void*)(&ldsB[ldsOff[i] * 8]),
            16, 0, 0);
      }
      __syncthreads();

      // ---- compute: 2 k-steps of 32, 16 MFMAs each ----
      #pragma unroll
      for (int kk = 0; kk < BK; kk += 32) {
        const int c = (kk >> 3) + quad;
        bf16x8 af[4], bfr[4];
        #pragma unroll
        for (int rs = 0; rs < 4; ++rs) {
          int r = wy * 64 + rs * 16 + l16;
          af[rs] = *(const bf16x8*)&ldsA[(r * 8 + (c ^ (r & 7))) * 8];
        }
        #pragma unroll
        for (int ns = 0; ns < 4; ++ns) {
          int n = wx * 64 + ns * 16 + l16;
          bfr[ns] = *(const bf16x8*)&ldsB[(n * 8 + (c ^ (n & 7))) * 8];
        }
        #pragma unroll
        for (int rs = 0; rs < 4; ++rs)
          #pragma unroll
          for (int ns = 0; ns < 4; ++ns)
            acc[rs][ns] = __builtin_amdgcn_mfma_f32_16x16x32_bf16(
                af[rs], bfr[ns], acc[rs][ns], 0, 0, 0);
      }
      __syncthreads();
    }

    // ---- epilogue: tanh * proj, accumulate per-lane partials ----
    #pragma unroll
    for (int ns = 0; ns < 4; ++ns) {
      int n = n0 + wx * 64 + ns * 16 + l16;
      float p = proj[n];
      #pragma unroll
      for (int rs = 0; rs < 4; ++rs)
        #pragma unroll
        for (int g = 0; g < 4; ++g)
          sc[rs][g] += fast_tanh(acc[rs][ns][g]) * p;
    }
  }

  // reduce across the 16 lanes holding different n-columns, then atomicAdd
  #pragma unroll
  for (int rs = 0; rs < 4; ++rs)
    #pragma unroll
    for (int g = 0; g < 4; ++g) {
      float v = sc[rs][g];
      v += __shfl_xor(v, 1);
      v += __shfl_xor(v, 2);
      v += __shfl_xor(v, 4);
      v += __shfl_xor(v, 8);
      if (l16 == 0) {
        int row = m0 + wy * 64 + rs * 16 + quad * 4 + g;
        atomicAdd(&scores[row], v);
      }
    }
}

// ---------------- windowed softmax + weighted sum ----------------
__global__ void out_kernel(const float* __restrict__ x,
                           const float* __restrict__ scores,
                           const int* __restrict__ wp,
                           float* __restrict__ out) {
  int r = blockIdx.x;            // t*B + b
  int t = r >> 4, b = r & 15;
  int w = *wp;
  if (w > 8) w = 8;
  int h = threadIdx.x;
  const float4* x4 = (const float4*)x;
  float4* o4 = (float4*)out;
  size_t base = (size_t)r * 256 + h;
  if (t < w) { o4[base] = x4[base]; return; }
  float s[8];
  float mx = -1e30f;
  for (int j = 0; j < w; ++j) {
    s[j] = scores[(t - w + j) * B_DIM + b];
    mx = fmaxf(mx, s[j]);
  }
  float sum = 0.f;
  for (int j = 0; j < w; ++j) { s[j] = __expf(s[j] - mx); sum += s[j]; }
  float inv = 1.0f / sum;
  float4 o = {0.f, 0.f, 0.f, 0.f};
  for (int j = 0; j < w; ++j) {
    float a = s[j] * inv;
    float4 v = x4[((size_t)(t - w + j) * B_DIM + b) * 256 + h];
    o.x += a * v.x; o.y += a * v.y; o.z += a * v.z; o.w += a * v.w;
  }
  o4[base] = o;
}

extern "C" void kernel_launch(void* const* d_in, const int* in_sizes, int n_in,
                              void* d_out, int out_size, void* d_ws, size_t ws_size,
                              hipStream_t stream) {
  const float* x    = (const float*)d_in[0];
  const float* w    = (const float*)d_in[1];
  const float* proj = (const float*)d_in[2];
  const int*   wp   = (const int*)d_in[3];
  float* out = (float*)d_out;

  // scratch: Xb (64 MiB) + Wt (2 MiB) live inside d_out (128 MiB), both dead
  // before out_kernel writes d_out. scores (128 KB) in d_ws.
  unsigned short* Xb = (unsigned short*)d_out;
  unsigned short* Wt = (unsigned short*)((char*)d_out + (size_t)64 * 1024 * 1024);
  float* scores = (float*)d_ws;

  hipMemsetAsync(scores, 0, M_DIM * sizeof(float), stream);

  convert_x_kernel<<<M_DIM * H_DIM / 1024, 256, 0, stream>>>(x, Xb);
  transpose_w_kernel<<<dim3(32, 32), dim3(32, 8), 0, stream>>>(w, Wt);
  score_gemm_kernel<<<1024, 256, 0, stream>>>(Xb, Wt, proj, scores);
  out_kernel<<<M_DIM, 256, 0, stream>>>(x, scores, wp, out);
}

// Round 2
// 353.248 us; speedup vs baseline: 1.0480x; 1.0480x over previous
//
#include <hip/hip_runtime.h>
#include <stdint.h>

#define T_DIM 2048
#define B_DIM 16
#define H_DIM 1024
#define M_DIM (T_DIM * B_DIM)   // 32768 rows
#define BK 64
#define TCHUNK 8

typedef __attribute__((ext_vector_type(8))) short bf16x8;
typedef __attribute__((ext_vector_type(4))) float floatx4;

__device__ inline unsigned short f2bf(float f) {
  union { float f; unsigned int u; } c; c.f = f;
  unsigned int u = c.u;
  return (unsigned short)((u + 0x7FFFu + ((u >> 16) & 1u)) >> 16);  // RNE
}

__device__ inline float fast_tanh(float x) {
  float e = __expf(2.0f * x);
  return 1.0f - 2.0f / (e + 1.0f);
}

// ---------------- X fp32 -> bf16 ----------------
__global__ void convert_x_kernel(const float* __restrict__ x,
                                 unsigned short* __restrict__ xb) {
  size_t i = ((size_t)blockIdx.x * 256 + threadIdx.x) * 4;
  float4 v = *(const float4*)(x + i);
  ushort4 o;
  o.x = f2bf(v.x); o.y = f2bf(v.y); o.z = f2bf(v.z); o.w = f2bf(v.w);
  *(ushort4*)(xb + i) = o;
}

// ---------------- W[K][N] fp32 -> Wt[N][K] bf16 ----------------
__global__ void transpose_w_kernel(const float* __restrict__ w,
                                   unsigned short* __restrict__ wt) {
  __shared__ float tile[32][33];
  int tx = threadIdx.x, ty = threadIdx.y;
  int n0 = blockIdx.x * 32, k0 = blockIdx.y * 32;
  for (int i = ty; i < 32; i += 8)
    tile[i][tx] = w[(size_t)(k0 + i) * H_DIM + n0 + tx];
  __syncthreads();
  for (int i = ty; i < 32; i += 8)
    wt[(size_t)(n0 + i) * H_DIM + k0 + tx] = f2bf(tile[tx][i]);
}

// ---------------- scores = tanh(X@W)@proj ----------------
// XCD swizzle: the 4 N-splits of one 128-row A-slab get blockIdx values
// congruent mod 8 and within 24 of each other -> same XCD, dispatch-adjacent
// -> A-tile fetched once into that XCD's L2 and shared.
__global__ __launch_bounds__(256, 4)
void score_gemm_kernel(const unsigned short* __restrict__ Xb,
                       const unsigned short* __restrict__ Wt,
                       const float* __restrict__ proj,
                       float* __restrict__ scores) {
  __shared__ __align__(16) unsigned short ldsA[128 * BK];
  __shared__ __align__(16) unsigned short ldsB[128 * BK];

  const int tid  = threadIdx.x;
  const int lane = tid & 63;
  const int wave = tid >> 6;
  const int wy = wave >> 1, wx = wave & 1;
  const int quad = lane >> 4, l16 = lane & 15;

  // swizzled decode: idx = g*32 + split*8 + x7, bm = g*8 + x7
  const int idx   = blockIdx.x;
  const int x7    = idx & 7;
  const int split = (idx >> 3) & 3;
  const int g     = idx >> 5;
  const int bm    = g * 8 + x7;        // 0..255
  const int m0    = bm * 128;
  const int nbase = split * 256;

  int ldsOff[4];
  int rowOff[4];
  #pragma unroll
  for (int i = 0; i < 4; ++i) {
    int cb = (i * 4 + wave) * 64;
    int s = cb + lane;
    int row = s >> 3, cs = s & 7;
    int cg = cs ^ (row & 7);
    ldsOff[i] = cb;
    rowOff[i] = row * H_DIM + cg * 8;
  }

  float sc[4][4];
  #pragma unroll
  for (int a = 0; a < 4; ++a)
    #pragma unroll
    for (int b = 0; b < 4; ++b) sc[a][b] = 0.0f;

  for (int n0 = nbase; n0 < nbase + 256; n0 += 128) {
    floatx4 acc[4][4];
    #pragma unroll
    for (int a = 0; a < 4; ++a)
      #pragma unroll
      for (int b = 0; b < 4; ++b) acc[a][b] = (floatx4){0.f, 0.f, 0.f, 0.f};

    for (int k0 = 0; k0 < H_DIM; k0 += BK) {
      #pragma unroll
      for (int i = 0; i < 4; ++i) {
        const unsigned short* ga = Xb + (size_t)m0 * H_DIM + rowOff[i] + k0;
        __builtin_amdgcn_global_load_lds(
            (const __attribute__((address_space(1))) void*)ga,
            (__attribute__((address_space(3))) void*)(&ldsA[ldsOff[i] * 8]),
            16, 0, 0);
        const unsigned short* gb = Wt + (size_t)n0 * H_DIM + rowOff[i] + k0;
        __builtin_amdgcn_global_load_lds(
            (const __attribute__((address_space(1))) void*)gb,
            (__attribute__((address_space(3))) void*)(&ldsB[ldsOff[i] * 8]),
            16, 0, 0);
      }
      __syncthreads();

      #pragma unroll
      for (int kk = 0; kk < BK; kk += 32) {
        const int c = (kk >> 3) + quad;
        bf16x8 af[4], bfr[4];
        #pragma unroll
        for (int rs = 0; rs < 4; ++rs) {
          int r = wy * 64 + rs * 16 + l16;
          af[rs] = *(const bf16x8*)&ldsA[(r * 8 + (c ^ (r & 7))) * 8];
        }
        #pragma unroll
        for (int ns = 0; ns < 4; ++ns) {
          int n = wx * 64 + ns * 16 + l16;
          bfr[ns] = *(const bf16x8*)&ldsB[(n * 8 + (c ^ (n & 7))) * 8];
        }
        #pragma unroll
        for (int rs = 0; rs < 4; ++rs)
          #pragma unroll
          for (int ns = 0; ns < 4; ++ns)
            acc[rs][ns] = __builtin_amdgcn_mfma_f32_16x16x32_bf16(
                af[rs], bfr[ns], acc[rs][ns], 0, 0, 0);
      }
      __syncthreads();
    }

    #pragma unroll
    for (int ns = 0; ns < 4; ++ns) {
      int n = n0 + wx * 64 + ns * 16 + l16;
      float p = proj[n];
      #pragma unroll
      for (int rs = 0; rs < 4; ++rs)
        #pragma unroll
        for (int gg = 0; gg < 4; ++gg)
          sc[rs][gg] += fast_tanh(acc[rs][ns][gg]) * p;
    }
  }

  #pragma unroll
  for (int rs = 0; rs < 4; ++rs)
    #pragma unroll
    for (int gg = 0; gg < 4; ++gg) {
      float v = sc[rs][gg];
      v += __shfl_xor(v, 1);
      v += __shfl_xor(v, 2);
      v += __shfl_xor(v, 4);
      v += __shfl_xor(v, 8);
      if (l16 == 0) {
        int row = m0 + wy * 64 + rs * 16 + quad * 4 + gg;
        atomicAdd(&scores[row], v);
      }
    }
}

// ---------------- windowed softmax + weighted sum ----------------
// Specialized w==3 path: each block computes TCHUNK consecutive t for one b,
// sliding the 3 window taps (float4) + 3 scores through registers.
// Exactly 1 row load + 1 row store per t.
__global__ void out_kernel(const float* __restrict__ x,
                           const float* __restrict__ scores,
                           const int* __restrict__ wp,
                           float* __restrict__ out) {
  int w = *wp;
  int t0 = blockIdx.x * TCHUNK;
  int b  = blockIdx.y;
  int h  = threadIdx.x;                    // float4 index within row
  const float4* x4 = (const float4*)x;
  float4* o4 = (float4*)out;

  if (w == 3) {
    float4 z = {0.f, 0.f, 0.f, 0.f};
    float4 a0, a1, a2;
    float  s0, s1, s2;
    {
      int tm = t0 - 3;
      a0 = (tm >= 0) ? x4[((size_t)tm * B_DIM + b) * 256 + h] : z;
      s0 = (tm >= 0) ? scores[tm * B_DIM + b] : 0.f;
      tm = t0 - 2;
      a1 = (tm >= 0) ? x4[((size_t)tm * B_DIM + b) * 256 + h] : z;
      s1 = (tm >= 0) ? scores[tm * B_DIM + b] : 0.f;
      tm = t0 - 1;
      a2 = (tm >= 0) ? x4[((size_t)tm * B_DIM + b) * 256 + h] : z;
      s2 = (tm >= 0) ? scores[tm * B_DIM + b] : 0.f;
    }
    #pragma unroll
    for (int i = 0; i < TCHUNK; ++i) {
      int t = t0 + i;
      size_t rbase = ((size_t)t * B_DIM + b) * 256 + h;
      float4 v = x4[rbase];                // row t (tap for t+1..t+3)
      float  sv = scores[t * B_DIM + b];
      if (t < 3) {
        o4[rbase] = v;
      } else {
        float m = fmaxf(fmaxf(s0, s1), s2);
        float e0 = __expf(s0 - m), e1 = __expf(s1 - m), e2 = __expf(s2 - m);
        float inv = 1.0f / (e0 + e1 + e2);
        e0 *= inv; e1 *= inv; e2 *= inv;
        float4 o;
        o.x = e0 * a0.x + e1 * a1.x + e2 * a2.x;
        o.y = e0 * a0.y + e1 * a1.y + e2 * a2.y;
        o.z = e0 * a0.z + e1 * a1.z + e2 * a2.z;
        o.w = e0 * a0.w + e1 * a1.w + e2 * a2.w;
        o4[rbase] = o;
      }
      a0 = a1; a1 = a2; a2 = v;
      s0 = s1; s1 = s2; s2 = sv;
    }
  } else {
    // generic fallback, w <= 8
    if (w > 8) w = 8;
    for (int i = 0; i < TCHUNK; ++i) {
      int t = t0 + i;
      size_t rbase = ((size_t)t * B_DIM + b) * 256 + h;
      if (t < w) { o4[rbase] = x4[rbase]; continue; }
      float s[8];
      float mx = -1e30f;
      for (int j = 0; j < w; ++j) {
        s[j] = scores[(t - w + j) * B_DIM + b];
        mx = fmaxf(mx, s[j]);
      }
      float sum = 0.f;
      for (int j = 0; j < w; ++j) { s[j] = __expf(s[j] - mx); sum += s[j]; }
      float inv = 1.0f / sum;
      float4 o = {0.f, 0.f, 0.f, 0.f};
      for (int j = 0; j < w; ++j) {
        float a = s[j] * inv;
        float4 v = x4[((size_t)(t - w + j) * B_DIM + b) * 256 + h];
        o.x += a * v.x; o.y += a * v.y; o.z += a * v.z; o.w += a * v.w;
      }
      o4[rbase] = o;
    }
  }
}

extern "C" void kernel_launch(void* const* d_in, const int* in_sizes, int n_in,
                              void* d_out, int out_size, void* d_ws, size_t ws_size,
                              hipStream_t stream) {
  const float* x    = (const float*)d_in[0];
  const float* w    = (const float*)d_in[1];
  const float* proj = (const float*)d_in[2];
  const int*   wp   = (const int*)d_in[3];
  float* out = (float*)d_out;

  unsigned short* Xb = (unsigned short*)d_out;
  unsigned short* Wt = (unsigned short*)((char*)d_out + (size_t)64 * 1024 * 1024);
  float* scores = (float*)d_ws;

  hipMemsetAsync(scores, 0, M_DIM * sizeof(float), stream);

  convert_x_kernel<<<M_DIM * H_DIM / 1024, 256, 0, stream>>>(x, Xb);
  transpose_w_kernel<<<dim3(32, 32), dim3(32, 8), 0, stream>>>(w, Wt);
  score_gemm_kernel<<<1024, 256, 0, stream>>>(Xb, Wt, proj, scores);
  out_kernel<<<dim3(T_DIM / TCHUNK, B_DIM), 256, 0, stream>>>(x, scores, wp, out);
}

// Round 3
// 333.119 us; speedup vs baseline: 1.1113x; 1.0604x over previous
//
#include <hip/hip_runtime.h>
#include <stdint.h>

#define T_DIM 2048
#define B_DIM 16
#define H_DIM 1024
#define M_DIM (T_DIM * B_DIM)   // 32768 rows
#define BK 64
#define TCHUNK 32

typedef __attribute__((ext_vector_type(8))) short bf16x8;
typedef __attribute__((ext_vector_type(4))) float floatx4;

__device__ inline unsigned short f2bf(float f) {
  union { float f; unsigned int u; } c; c.f = f;
  unsigned int u = c.u;
  return (unsigned short)((u + 0x7FFFu + ((u >> 16) & 1u)) >> 16);  // RNE
}

__device__ inline float bf2f(unsigned short u) {
  union { float f; unsigned int u; } c; c.u = ((unsigned int)u) << 16;
  return c.f;
}

__device__ inline float fast_tanh(float x) {
  float e = __expf(2.0f * x);
  return 1.0f - 2.0f / (e + 1.0f);
}

// ---------------- X fp32 -> bf16 ----------------
__global__ void convert_x_kernel(const float* __restrict__ x,
                                 unsigned short* __restrict__ xb) {
  size_t i = ((size_t)blockIdx.x * 256 + threadIdx.x) * 4;
  float4 v = *(const float4*)(x + i);
  ushort4 o;
  o.x = f2bf(v.x); o.y = f2bf(v.y); o.z = f2bf(v.z); o.w = f2bf(v.w);
  *(ushort4*)(xb + i) = o;
}

// ---------------- W[K][N] fp32 -> Wt[N][K] bf16 ----------------
__global__ void transpose_w_kernel(const float* __restrict__ w,
                                   unsigned short* __restrict__ wt) {
  __shared__ float tile[32][33];
  int tx = threadIdx.x, ty = threadIdx.y;
  int n0 = blockIdx.x * 32, k0 = blockIdx.y * 32;
  for (int i = ty; i < 32; i += 8)
    tile[i][tx] = w[(size_t)(k0 + i) * H_DIM + n0 + tx];
  __syncthreads();
  for (int i = ty; i < 32; i += 8)
    wt[(size_t)(n0 + i) * H_DIM + k0 + tx] = f2bf(tile[tx][i]);
}

// ---------------- scores = tanh(X@W)@proj ----------------
// XCD swizzle: 4 N-splits of one 128-row A-slab land on the same XCD,
// dispatch-adjacent -> A fetched once per XCD (R2: FETCH 266->74 MB).
__global__ __launch_bounds__(256, 4)
void score_gemm_kernel(const unsigned short* __restrict__ Xb,
                       const unsigned short* __restrict__ Wt,
                       const float* __restrict__ proj,
                       float* __restrict__ scores) {
  __shared__ __align__(16) unsigned short ldsA[128 * BK];
  __shared__ __align__(16) unsigned short ldsB[128 * BK];

  const int tid  = threadIdx.x;
  const int lane = tid & 63;
  const int wave = tid >> 6;
  const int wy = wave >> 1, wx = wave & 1;
  const int quad = lane >> 4, l16 = lane & 15;

  const int idx   = blockIdx.x;
  const int x7    = idx & 7;
  const int split = (idx >> 3) & 3;
  const int g     = idx >> 5;
  const int bm    = g * 8 + x7;        // 0..255
  const int m0    = bm * 128;
  const int nbase = split * 256;

  int ldsOff[4];
  int rowOff[4];
  #pragma unroll
  for (int i = 0; i < 4; ++i) {
    int cb = (i * 4 + wave) * 64;
    int s = cb + lane;
    int row = s >> 3, cs = s & 7;
    int cg = cs ^ (row & 7);
    ldsOff[i] = cb;
    rowOff[i] = row * H_DIM + cg * 8;
  }

  float sc[4][4];
  #pragma unroll
  for (int a = 0; a < 4; ++a)
    #pragma unroll
    for (int b = 0; b < 4; ++b) sc[a][b] = 0.0f;

  for (int n0 = nbase; n0 < nbase + 256; n0 += 128) {
    floatx4 acc[4][4];
    #pragma unroll
    for (int a = 0; a < 4; ++a)
      #pragma unroll
      for (int b = 0; b < 4; ++b) acc[a][b] = (floatx4){0.f, 0.f, 0.f, 0.f};

    for (int k0 = 0; k0 < H_DIM; k0 += BK) {
      #pragma unroll
      for (int i = 0; i < 4; ++i) {
        const unsigned short* ga = Xb + (size_t)m0 * H_DIM + rowOff[i] + k0;
        __builtin_amdgcn_global_load_lds(
            (const __attribute__((address_space(1))) void*)ga,
            (__attribute__((address_space(3))) void*)(&ldsA[ldsOff[i] * 8]),
            16, 0, 0);
        const unsigned short* gb = Wt + (size_t)n0 * H_DIM + rowOff[i] + k0;
        __builtin_amdgcn_global_load_lds(
            (const __attribute__((address_space(1))) void*)gb,
            (__attribute__((address_space(3))) void*)(&ldsB[ldsOff[i] * 8]),
            16, 0, 0);
      }
      __syncthreads();

      #pragma unroll
      for (int kk = 0; kk < BK; kk += 32) {
        const int c = (kk >> 3) + quad;
        bf16x8 af[4], bfr[4];
        #pragma unroll
        for (int rs = 0; rs < 4; ++rs) {
          int r = wy * 64 + rs * 16 + l16;
          af[rs] = *(const bf16x8*)&ldsA[(r * 8 + (c ^ (r & 7))) * 8];
        }
        #pragma unroll
        for (int ns = 0; ns < 4; ++ns) {
          int n = wx * 64 + ns * 16 + l16;
          bfr[ns] = *(const bf16x8*)&ldsB[(n * 8 + (c ^ (n & 7))) * 8];
        }
        #pragma unroll
        for (int rs = 0; rs < 4; ++rs)
          #pragma unroll
          for (int ns = 0; ns < 4; ++ns)
            acc[rs][ns] = __builtin_amdgcn_mfma_f32_16x16x32_bf16(
                af[rs], bfr[ns], acc[rs][ns], 0, 0, 0);
      }
      __syncthreads();
    }

    #pragma unroll
    for (int ns = 0; ns < 4; ++ns) {
      int n = n0 + wx * 64 + ns * 16 + l16;
      float p = proj[n];
      #pragma unroll
      for (int rs = 0; rs < 4; ++rs)
        #pragma unroll
        for (int gg = 0; gg < 4; ++gg)
          sc[rs][gg] += fast_tanh(acc[rs][ns][gg]) * p;
    }
  }

  #pragma unroll
  for (int rs = 0; rs < 4; ++rs)
    #pragma unroll
    for (int gg = 0; gg < 4; ++gg) {
      float v = sc[rs][gg];
      v += __shfl_xor(v, 1);
      v += __shfl_xor(v, 2);
      v += __shfl_xor(v, 4);
      v += __shfl_xor(v, 8);
      if (l16 == 0) {
        int row = m0 + wy * 64 + rs * 16 + quad * 4 + gg;
        atomicAdd(&scores[row], v);
      }
    }
}

// ---------------- windowed softmax + weighted sum (bf16 taps) ----------------
// w==3 fast path: TCHUNK consecutive t per block for one b; 3 taps read from
// Xb (bf16, half the bytes), t<3 passthrough reads exact fp32 x.
__global__ void out_kernel_bf16(const float* __restrict__ x,
                                const unsigned short* __restrict__ xb,
                                const float* __restrict__ scores,
                                const int* __restrict__ wp,
                                float* __restrict__ out) {
  int w = *wp;
  int t0 = blockIdx.x * TCHUNK;
  int b  = blockIdx.y;
  int h  = threadIdx.x;                 // 4-element group within row
  const float4* x4 = (const float4*)x;
  float4* o4 = (float4*)out;
  const ushort4* xb4 = (const ushort4*)xb;

  if (w == 3) {
    float4 z = {0.f, 0.f, 0.f, 0.f};
    float4 a0, a1, a2;
    float  s0, s1, s2;
    #pragma unroll
    for (int j = 0; j < 3; ++j) {
      int tm = t0 - 3 + j;
      float4 a = z; float s = 0.f;
      if (tm >= 0) {
        ushort4 u = xb4[((size_t)tm * B_DIM + b) * 256 + h];
        a.x = bf2f(u.x); a.y = bf2f(u.y); a.z = bf2f(u.z); a.w = bf2f(u.w);
        s = scores[tm * B_DIM + b];
      }
      if (j == 0) { a0 = a; s0 = s; }
      else if (j == 1) { a1 = a; s1 = s; }
      else { a2 = a; s2 = s; }
    }
    for (int i = 0; i < TCHUNK; ++i) {
      int t = t0 + i;
      size_t rbase = ((size_t)t * B_DIM + b) * 256 + h;
      ushort4 u = xb4[rbase];
      float4 v;
      v.x = bf2f(u.x); v.y = bf2f(u.y); v.z = bf2f(u.z); v.w = bf2f(u.w);
      float sv = scores[t * B_DIM + b];
      if (t < 3) {
        o4[rbase] = x4[rbase];           // exact fp32 passthrough
      } else {
        float m = fmaxf(fmaxf(s0, s1), s2);
        float e0 = __expf(s0 - m), e1 = __expf(s1 - m), e2 = __expf(s2 - m);
        float inv = 1.0f / (e0 + e1 + e2);
        e0 *= inv; e1 *= inv; e2 *= inv;
        float4 o;
        o.x = e0 * a0.x + e1 * a1.x + e2 * a2.x;
        o.y = e0 * a0.y + e1 * a1.y + e2 * a2.y;
        o.z = e0 * a0.z + e1 * a1.z + e2 * a2.z;
        o.w = e0 * a0.w + e1 * a1.w + e2 * a2.w;
        o4[rbase] = o;
      }
      a0 = a1; a1 = a2; a2 = v;
      s0 = s1; s1 = s2; s2 = sv;
    }
  } else {
    if (w > 8) w = 8;
    for (int i = 0; i < TCHUNK; ++i) {
      int t = t0 + i;
      size_t rbase = ((size_t)t * B_DIM + b) * 256 + h;
      if (t < w) { o4[rbase] = x4[rbase]; continue; }
      float s[8];
      float mx = -1e30f;
      for (int j = 0; j < w; ++j) {
        s[j] = scores[(t - w + j) * B_DIM + b];
        mx = fmaxf(mx, s[j]);
      }
      float sum = 0.f;
      for (int j = 0; j < w; ++j) { s[j] = __expf(s[j] - mx); sum += s[j]; }
      float inv = 1.0f / sum;
      float4 o = {0.f, 0.f, 0.f, 0.f};
      for (int j = 0; j < w; ++j) {
        float a = s[j] * inv;
        float4 v = x4[((size_t)(t - w + j) * B_DIM + b) * 256 + h];
        o.x += a * v.x; o.y += a * v.y; o.z += a * v.z; o.w += a * v.w;
      }
      o4[rbase] = o;
    }
  }
}

// ---------------- fp32-tap fallback (Xb aliases d_out; can't read it here) --
__global__ void out_kernel_f32(const float* __restrict__ x,
                               const float* __restrict__ scores,
                               const int* __restrict__ wp,
                               float* __restrict__ out) {
  int w = *wp;
  int t0 = blockIdx.x * TCHUNK;
  int b  = blockIdx.y;
  int h  = threadIdx.x;
  const float4* x4 = (const float4*)x;
  float4* o4 = (float4*)out;

  if (w == 3) {
    float4 z = {0.f, 0.f, 0.f, 0.f};
    float4 a0, a1, a2;
    float  s0, s1, s2;
    {
      int tm = t0 - 3;
      a0 = (tm >= 0) ? x4[((size_t)tm * B_DIM + b) * 256 + h] : z;
      s0 = (tm >= 0) ? scores[tm * B_DIM + b] : 0.f;
      tm = t0 - 2;
      a1 = (tm >= 0) ? x4[((size_t)tm * B_DIM + b) * 256 + h] : z;
      s1 = (tm >= 0) ? scores[tm * B_DIM + b] : 0.f;
      tm = t0 - 1;
      a2 = (tm >= 0) ? x4[((size_t)tm * B_DIM + b) * 256 + h] : z;
      s2 = (tm >= 0) ? scores[tm * B_DIM + b] : 0.f;
    }
    for (int i = 0; i < TCHUNK; ++i) {
      int t = t0 + i;
      size_t rbase = ((size_t)t * B_DIM + b) * 256 + h;
      float4 v = x4[rbase];
      float  sv = scores[t * B_DIM + b];
      if (t < 3) {
        o4[rbase] = v;
      } else {
        float m = fmaxf(fmaxf(s0, s1), s2);
        float e0 = __expf(s0 - m), e1 = __expf(s1 - m), e2 = __expf(s2 - m);
        float inv = 1.0f / (e0 + e1 + e2);
        e0 *= inv; e1 *= inv; e2 *= inv;
        float4 o;
        o.x = e0 * a0.x + e1 * a1.x + e2 * a2.x;
        o.y = e0 * a0.y + e1 * a1.y + e2 * a2.y;
        o.z = e0 * a0.z + e1 * a1.z + e2 * a2.z;
        o.w = e0 * a0.w + e1 * a1.w + e2 * a2.w;
        o4[rbase] = o;
      }
      a0 = a1; a1 = a2; a2 = v;
      s0 = s1; s1 = s2; s2 = sv;
    }
  } else {
    if (w > 8) w = 8;
    for (int i = 0; i < TCHUNK; ++i) {
      int t = t0 + i;
      size_t rbase = ((size_t)t * B_DIM + b) * 256 + h;
      if (t < w) { o4[rbase] = x4[rbase]; continue; }
      float s[8];
      float mx = -1e30f;
      for (int j = 0; j < w; ++j) {
        s[j] = scores[(t - w + j) * B_DIM + b];
        mx = fmaxf(mx, s[j]);
      }
      float sum = 0.f;
      for (int j = 0; j < w; ++j) { s[j] = __expf(s[j] - mx); sum += s[j]; }
      float inv = 1.0f / sum;
      float4 o = {0.f, 0.f, 0.f, 0.f};
      for (int j = 0; j < w; ++j) {
        float a = s[j] * inv;
        float4 v = x4[((size_t)(t - w + j) * B_DIM + b) * 256 + h];
        o.x += a * v.x; o.y += a * v.y; o.z += a * v.z; o.w += a * v.w;
      }
      o4[rbase] = o;
    }
  }
}

extern "C" void kernel_launch(void* const* d_in, const int* in_sizes, int n_in,
                              void* d_out, int out_size, void* d_ws, size_t ws_size,
                              hipStream_t stream) {
  const float* x    = (const float*)d_in[0];
  const float* w    = (const float*)d_in[1];
  const float* proj = (const float*)d_in[2];
  const int*   wp   = (const int*)d_in[3];
  float* out = (float*)d_out;

  // Preferred layout: everything in d_ws (Xb 64 MiB, Wt 2 MiB, scores 128 KiB)
  // so out_kernel can read bf16 taps without aliasing its own d_out writes.
  // ws_size is constant across calls -> branch is graph-capture-safe.
  const size_t XB_BYTES = (size_t)64 * 1024 * 1024;
  const size_t WT_BYTES = (size_t)2 * 1024 * 1024;
  const size_t need = XB_BYTES + WT_BYTES + (size_t)M_DIM * sizeof(float);
  const bool use_ws = ws_size >= need;

  unsigned short* Xb;
  unsigned short* Wt;
  float* scores;
  if (use_ws) {
    Xb = (unsigned short*)d_ws;
    Wt = (unsigned short*)((char*)d_ws + XB_BYTES);
    scores = (float*)((char*)d_ws + XB_BYTES + WT_BYTES);
  } else {
    Xb = (unsigned short*)d_out;
    Wt = (unsigned short*)((char*)d_out + XB_BYTES);
    scores = (float*)d_ws;
  }

  hipMemsetAsync(scores, 0, M_DIM * sizeof(float), stream);

  convert_x_kernel<<<M_DIM * H_DIM / 1024, 256, 0, stream>>>(x, Xb);
  transpose_w_kernel<<<dim3(32, 32), dim3(32, 8), 0, stream>>>(w, Wt);
  score_gemm_kernel<<<1024, 256, 0, stream>>>(Xb, Wt, proj, scores);
  if (use_ws)
    out_kernel_bf16<<<dim3(T_DIM / TCHUNK, B_DIM), 256, 0, stream>>>(x, Xb, scores, wp, out);
  else
    out_kernel_f32<<<dim3(T_DIM / TCHUNK, B_DIM), 256, 0, stream>>>(x, scores, wp, out);
}